// Round 10
// baseline (1150.490 us; speedup 1.0000x reference)
//
#include <hip/hip_runtime.h>
#include <math.h>

#define NQ 10
#define DIM 1024
#define NL 2

// ---------------------------------------------------------------------------
// Precompute the 20 Rot gate matrices into workspace.
// Per gate 8 floats: u00r,u00i,u01r,u01i,u10r,u10i,u11r,u11i
// Rot(phi,theta,omega) = RZ(omega) RY(theta) RZ(phi)
// ---------------------------------------------------------------------------
__global__ void precompute_gates(const float* __restrict__ w, float* __restrict__ g) {
    int t = threadIdx.x;
    if (t < NL * NQ) {
        float phi = w[t * 3 + 0], theta = w[t * 3 + 1], omega = w[t * 3 + 2];
        float c  = cosf(0.5f * theta), s = sinf(0.5f * theta);
        float ap = 0.5f * phi, ao = 0.5f * omega;
        float cs = cosf(ap + ao), ss = sinf(ap + ao);
        float cd = cosf(ap - ao), sd = sinf(ap - ao);
        float* o = g + t * 8;
        o[0] =  c * cs;  o[1] = -c * ss;   // u00
        o[2] = -s * cd;  o[3] = -s * sd;   // u01
        o[4] =  s * cd;  o[5] = -s * sd;   // u10
        o[6] =  c * cs;  o[7] =  c * ss;   // u11
    }
}

// ---------------------------------------------------------------------------
// Cross-lane primitives (see round-8 notes; builtin swap is mandatory —
// naive asm("+v","+v") coalesces equal-valued d,s into one reg -> garbage).
//   xor1 -> DPP quad_perm 0xB1; xor2 -> 0x4E; xor8 -> row_ror:8 (0x128)
//   xor4 -> ds_swizzle 0x101F; xor16/32 -> v_permlaneN_swap_b32
// permlaneN_swap(d,s) with d=s=v: (lane&LM)==0: mine=d',partner=s';
// else mine=s',partner=d'. Butterfly sum = d'+s' (no select).
// ---------------------------------------------------------------------------
template<int CTRL>
__device__ __forceinline__ float dppmov(float v) {
    return __int_as_float(
        __builtin_amdgcn_mov_dpp(__float_as_int(v), CTRL, 0xF, 0xF, true));
}

typedef unsigned u32x2 __attribute__((ext_vector_type(2)));

template<int LM>
__device__ __forceinline__ void plswap(float& d, float& s) {
#if __has_builtin(__builtin_amdgcn_permlane16_swap) && __has_builtin(__builtin_amdgcn_permlane32_swap)
    u32x2 r;
    if constexpr (LM == 16)
        r = __builtin_amdgcn_permlane16_swap(__float_as_uint(d), __float_as_uint(s), false, false);
    else
        r = __builtin_amdgcn_permlane32_swap(__float_as_uint(d), __float_as_uint(s), false, false);
    d = __uint_as_float(r.x);
    s = __uint_as_float(r.y);
#else
    asm("v_mov_b32 %0, %1" : "=v"(s) : "v"(s));
    if constexpr (LM == 16) asm("v_permlane16_swap_b32 %0, %1" : "+v"(d), "+v"(s));
    else                    asm("v_permlane32_swap_b32 %0, %1" : "+v"(d), "+v"(s));
#endif
}

// partner value v[lane ^ LM], LM in {1,2,4,8}
template<int LM>
__device__ __forceinline__ float xfetch(float v) {
    if constexpr (LM == 1)      return dppmov<0xB1>(v);
    else if constexpr (LM == 2) return dppmov<0x4E>(v);
    else if constexpr (LM == 4)
        return __int_as_float(__builtin_amdgcn_ds_swizzle(__float_as_int(v), 0x101F));
    else                        return dppmov<0x128>(v);   // LM == 8
}

template<int LM>
__device__ __forceinline__ float bfly_add(float v) {
    if constexpr (LM >= 16) { float d = v, s = v; plswap<LM>(d, s); return d + s; }
    else                    return v + xfetch<LM>(v);
}

__device__ __forceinline__ float bfly_full(float v) {
    v = bfly_add<1>(v); v = bfly_add<2>(v); v = bfly_add<4>(v);
    v = bfly_add<8>(v); v = bfly_add<16>(v); v = bfly_add<32>(v);
    return v;
}

// ---------------------------------------------------------------------------
// Rot gate on bit position P (P = 9 - wire). Bits 0-3 in-register, 4-9 lane.
// ---------------------------------------------------------------------------
template<int P>
__device__ __forceinline__ void apply_rot(float (&re)[16], float (&im)[16],
                                          const float* __restrict__ g, int lane) {
    float u00r = g[0], u00i = g[1], u01r = g[2], u01i = g[3];
    float u10r = g[4], u10i = g[5], u11r = g[6], u11i = g[7];
    if constexpr (P <= 3) {
        constexpr int m = 1 << P;
        #pragma unroll
        for (int r = 0; r < 16; ++r) {
            if (!(r & m)) {
                const int r2 = r | m;
                float a0r = re[r], a0i = im[r], a1r = re[r2], a1i = im[r2];
                re[r]  = u00r * a0r - u00i * a0i + u01r * a1r - u01i * a1i;
                im[r]  = u00r * a0i + u00i * a0r + u01r * a1i + u01i * a1r;
                re[r2] = u10r * a0r - u10i * a0i + u11r * a1r - u11i * a1i;
                im[r2] = u10r * a0i + u10i * a0r + u11r * a1i + u11i * a1r;
            }
        }
    } else if constexpr (P <= 7) {
        constexpr int LM = 1 << (P - 4);           // 1,2,4,8
        const bool hi = (lane & LM) != 0;
        // out = A*mine + B*partner
        float Ar = hi ? u11r : u00r, Ai = hi ? u11i : u00i;
        float Br = hi ? u10r : u01r, Bi = hi ? u10i : u01i;
        #pragma unroll
        for (int r = 0; r < 16; ++r) {
            float pr = xfetch<LM>(re[r]), pi = xfetch<LM>(im[r]);
            float mr = re[r], mi = im[r];
            re[r] = Ar * mr - Ai * mi + Br * pr - Bi * pi;
            im[r] = Ar * mi + Ai * mr + Br * pi + Bi * pr;
        }
    } else {
        constexpr int LM = 1 << (P - 4);           // 16 or 32
        const bool hi = (lane & LM) != 0;
        // out = Cd*d' + Cs*s'  (selection folded into coefficients)
        float Cdr = hi ? u10r : u00r, Cdi = hi ? u10i : u00i;
        float Csr = hi ? u11r : u01r, Csi = hi ? u11i : u01i;
        #pragma unroll
        for (int r = 0; r < 16; ++r) {
            float dr = re[r], sr = re[r]; plswap<LM>(dr, sr);
            float di = im[r], si = im[r]; plswap<LM>(di, si);
            re[r] = Cdr * dr - Cdi * di + Csr * sr - Csi * si;
            im[r] = Cdr * di + Cdi * dr + Csr * si + Csi * sr;
        }
    }
}

// ---------------------------------------------------------------------------
// CNOT with control bit PC, target bit PT.
// ---------------------------------------------------------------------------
template<int PC, int PT>
__device__ __forceinline__ void apply_cnot(float (&re)[16], float (&im)[16], int lane) {
    if constexpr (PC >= 4 && PT >= 4) {
        constexpr int LM = 1 << (PT - 4);
        const bool ctrl = (lane & (1 << (PC - 4))) != 0;
        if constexpr (LM >= 16) {
            const bool t = (lane & LM) != 0;
            const bool sel = (ctrl == t);          // out = sel ? d' : s'
            #pragma unroll
            for (int r = 0; r < 16; ++r) {
                float dr = re[r], sr = re[r]; plswap<LM>(dr, sr);
                float di = im[r], si = im[r]; plswap<LM>(di, si);
                re[r] = sel ? dr : sr;
                im[r] = sel ? di : si;
            }
        } else {
            #pragma unroll
            for (int r = 0; r < 16; ++r) {
                float pr = xfetch<LM>(re[r]), pi = xfetch<LM>(im[r]);
                re[r] = ctrl ? pr : re[r];
                im[r] = ctrl ? pi : im[r];
            }
        }
    } else if constexpr (PC >= 4 && PT <= 3) {
        constexpr int m = 1 << PT;
        const bool ctrl = (lane & (1 << (PC - 4))) != 0;
        #pragma unroll
        for (int r = 0; r < 16; ++r) {
            if (!(r & m)) {
                const int r2 = r | m;
                float t0r = re[r], t0i = im[r], t1r = re[r2], t1i = im[r2];
                re[r]  = ctrl ? t1r : t0r;  im[r]  = ctrl ? t1i : t0i;
                re[r2] = ctrl ? t0r : t1r;  im[r2] = ctrl ? t0i : t1i;
            }
        }
    } else if constexpr (PC <= 3 && PT >= 4) {
        constexpr int LM = 1 << (PT - 4);
        constexpr int cm = 1 << PC;
        if constexpr (LM >= 16) {
            const bool t = (lane & LM) != 0;       // partner = t ? d' : s'
            #pragma unroll
            for (int r = 0; r < 16; ++r) {
                if (r & cm) {
                    float dr = re[r], sr = re[r]; plswap<LM>(dr, sr);
                    float di = im[r], si = im[r]; plswap<LM>(di, si);
                    re[r] = t ? dr : sr;
                    im[r] = t ? di : si;
                }
            }
        } else {
            #pragma unroll
            for (int r = 0; r < 16; ++r) {
                if (r & cm) {                      // compile-time, lane-uniform
                    re[r] = xfetch<LM>(re[r]);
                    im[r] = xfetch<LM>(im[r]);
                }
            }
        }
    } else {
        constexpr int cm = 1 << PC, tm = 1 << PT;
        #pragma unroll
        for (int r = 0; r < 16; ++r) {
            if ((r & cm) && !(r & tm)) {
                const int r2 = r | tm;
                float tr = re[r]; re[r] = re[r2]; re[r2] = tr;
                float ti = im[r]; im[r] = im[r2]; im[r2] = ti;
            }
        }
    }
}

// ---------------------------------------------------------------------------
// Main kernel: one wave per batch element; 4 waves per block.
// Amplitude k = (lane << 4) | r ; wire q <-> bit (9-q).
// __launch_bounds__(256, 8): force VGPR<=64 -> 8 waves/SIMD residency.
// ---------------------------------------------------------------------------
__global__ __launch_bounds__(256, 8) void qsim(const float* __restrict__ x,
                                               const float* __restrict__ gates,
                                               float* __restrict__ out, int B) {
    const int lane = threadIdx.x & 63;
    const int wave = threadIdx.x >> 6;
    const int row  = blockIdx.x * 4 + wave;
    if (row >= B) return;

    const float* xr = x + (size_t)row * DIM + lane * 16;
    float re[16], im[16];
    {
        float4 v0 = *(const float4*)(xr + 0);
        float4 v1 = *(const float4*)(xr + 4);
        float4 v2 = *(const float4*)(xr + 8);
        float4 v3 = *(const float4*)(xr + 12);
        re[0]=v0.x; re[1]=v0.y; re[2]=v0.z; re[3]=v0.w;
        re[4]=v1.x; re[5]=v1.y; re[6]=v1.z; re[7]=v1.w;
        re[8]=v2.x; re[9]=v2.y; re[10]=v2.z; re[11]=v2.w;
        re[12]=v3.x; re[13]=v3.y; re[14]=v3.z; re[15]=v3.w;
    }
    float nrm = 0.f;
    #pragma unroll
    for (int r = 0; r < 16; ++r) nrm += re[r] * re[r];
    nrm = bfly_full(nrm);
    float inv = rsqrtf(nrm);

    // ----- first gate (layer0, wire0, P=9): state is REAL; fold `inv` into
    // the coefficients (replaces the normalize pass + im-init; half the FMAs).
    {
        const float* g = gates;                    // gate (0,0)
        const bool hi = (lane & 32) != 0;
        float Cdr = (hi ? g[4] : g[0]) * inv, Cdi = (hi ? g[5] : g[1]) * inv;
        float Csr = (hi ? g[6] : g[2]) * inv, Csi = (hi ? g[7] : g[3]) * inv;
        #pragma unroll
        for (int r = 0; r < 16; ++r) {
            float dr = re[r], sr = re[r]; plswap<32>(dr, sr);
            re[r] = Cdr * dr + Csr * sr;
            im[r] = Cdi * dr + Csi * sr;
        }
    }

    #define ROT(l, q) apply_rot<9 - (q)>(re, im, gates + ((l) * 10 + (q)) * 8, lane)

    // ----- layer 0 (wire 0 done above): Rot rest, then CNOT ring r=1 -----
    ROT(0,1); ROT(0,2); ROT(0,3); ROT(0,4);
    ROT(0,5); ROT(0,6); ROT(0,7); ROT(0,8); ROT(0,9);
    apply_cnot<9,8>(re,im,lane); apply_cnot<8,7>(re,im,lane);
    apply_cnot<7,6>(re,im,lane); apply_cnot<6,5>(re,im,lane);
    apply_cnot<5,4>(re,im,lane); apply_cnot<4,3>(re,im,lane);
    apply_cnot<3,2>(re,im,lane); apply_cnot<2,1>(re,im,lane);
    apply_cnot<1,0>(re,im,lane); apply_cnot<0,9>(re,im,lane);

    // ----- layer 1: Rot all wires, then CNOT ring r=2 -----
    ROT(1,0); ROT(1,1); ROT(1,2); ROT(1,3); ROT(1,4);
    ROT(1,5); ROT(1,6); ROT(1,7); ROT(1,8); ROT(1,9);
    apply_cnot<9,7>(re,im,lane); apply_cnot<8,6>(re,im,lane);
    apply_cnot<7,5>(re,im,lane); apply_cnot<6,4>(re,im,lane);
    apply_cnot<5,3>(re,im,lane); apply_cnot<4,2>(re,im,lane);
    apply_cnot<3,1>(re,im,lane); apply_cnot<2,0>(re,im,lane);
    apply_cnot<1,9>(re,im,lane); apply_cnot<0,8>(re,im,lane);

    #undef ROT

    // ----- probabilities: accumulate on the fly (no p[16] array) -----
    // reg-bit qubits: q6<->mask8, q7<->4, q8<->2, q9<->1
    float sum = 0.f, s1a = 0.f, s1b = 0.f, s1c = 0.f, s1d = 0.f;
    #pragma unroll
    for (int r = 0; r < 16; ++r) {
        float t = re[r] * re[r] + im[r] * im[r];
        sum += t;
        if (r & 8) s1a += t;
        if (r & 4) s1b += t;
        if (r & 2) s1c += t;
        if (r & 1) s1d += t;
    }

    // ----- Walsh-Hadamard over the 6 lane bits: lane k=1<<(5-i) ends up
    // holding e_i ; lane 0 holds total probability. -----
    float w = sum;
    {
        float p, sg;
        sg = (lane & 1) ? -1.f : 1.f;  p = xfetch<1>(w); w = fmaf(sg, w, p);
        sg = (lane & 2) ? -1.f : 1.f;  p = xfetch<2>(w); w = fmaf(sg, w, p);
        sg = (lane & 4) ? -1.f : 1.f;  p = xfetch<4>(w); w = fmaf(sg, w, p);
        sg = (lane & 8) ? -1.f : 1.f;  p = xfetch<8>(w); w = fmaf(sg, w, p);
        { float d = w, s = w; plswap<16>(d, s); sg = (lane & 16) ? -1.f : 1.f; w = fmaf(sg, s, d); }
        { float d = w, s = w; plswap<32>(d, s); sg = (lane & 32) ? -1.f : 1.f; w = fmaf(sg, s, d); }
    }

    // ----- reg-bit qubit expvals: full butterfly sums of s1x -----
    float R0 = bfly_full(s1a);
    float R1 = bfly_full(s1b);
    float R2 = bfly_full(s1c);
    float R3 = bfly_full(s1d);

    float* o = out + (size_t)row * NQ;
    // lane-bit qubits: lanes 32,16,8,4,2,1 hold e[0..5]
    if (lane && lane <= 32 && !(lane & (lane - 1)))
        o[6 - __ffs(lane)] = w;
    // reg-bit qubits from lane 0 (w there == total probability)
    if (lane == 0) {
        o[6] = fmaf(-2.f, R0, w);
        o[7] = fmaf(-2.f, R1, w);
        o[8] = fmaf(-2.f, R2, w);
        o[9] = fmaf(-2.f, R3, w);
    }
}

extern "C" void kernel_launch(void* const* d_in, const int* in_sizes, int n_in,
                              void* d_out, int out_size, void* d_ws, size_t ws_size,
                              hipStream_t stream) {
    const float* x = (const float*)d_in[0];
    const float* w = (const float*)d_in[1];
    float* gates = (float*)d_ws;                  // 160 floats
    float* out = (float*)d_out;

    const int B = in_sizes[0] / DIM;              // 16384

    precompute_gates<<<1, 64, 0, stream>>>(w, gates);
    qsim<<<(B + 3) / 4, 256, 0, stream>>>(x, gates, out, B);
}

// Round 11
// 170.389 us; speedup vs baseline: 6.7521x; 6.7521x over previous
//
#include <hip/hip_runtime.h>
#include <math.h>

#define NQ 10
#define DIM 1024
#define NL 2

// ---------------------------------------------------------------------------
// Precompute the 20 Rot gate matrices into workspace.
// Per gate 8 floats: u00r,u00i,u01r,u01i,u10r,u10i,u11r,u11i
// ---------------------------------------------------------------------------
__global__ void precompute_gates(const float* __restrict__ w, float* __restrict__ g) {
    int t = threadIdx.x;
    if (t < NL * NQ) {
        float phi = w[t * 3 + 0], theta = w[t * 3 + 1], omega = w[t * 3 + 2];
        float c  = cosf(0.5f * theta), s = sinf(0.5f * theta);
        float ap = 0.5f * phi, ao = 0.5f * omega;
        float cs = cosf(ap + ao), ss = sinf(ap + ao);
        float cd = cosf(ap - ao), sd = sinf(ap - ao);
        float* o = g + t * 8;
        o[0] =  c * cs;  o[1] = -c * ss;   // u00
        o[2] = -s * cd;  o[3] = -s * sd;   // u01
        o[4] =  s * cd;  o[5] = -s * sd;   // u10
        o[6] =  c * cs;  o[7] =  c * ss;   // u11
    }
}

// ---------------------------------------------------------------------------
// Cross-lane primitives. Builtin permlane swap is mandatory (naive
// asm("+v","+v") coalesces equal-valued d,s into one reg -> self-swap bug).
// NOTE (round 10): NO __launch_bounds__ min-wave forcing — (256,8) forced
// VGPR=32, spilled the 32-reg state to scratch: 3.6GB writes, 6.8x slower.
// ---------------------------------------------------------------------------
template<int CTRL>
__device__ __forceinline__ float dppmov(float v) {
    return __int_as_float(
        __builtin_amdgcn_mov_dpp(__float_as_int(v), CTRL, 0xF, 0xF, true));
}

typedef unsigned u32x2 __attribute__((ext_vector_type(2)));
typedef float f2 __attribute__((ext_vector_type(2)));

template<int LM>
__device__ __forceinline__ void plswap(float& d, float& s) {
#if __has_builtin(__builtin_amdgcn_permlane16_swap) && __has_builtin(__builtin_amdgcn_permlane32_swap)
    u32x2 r;
    if constexpr (LM == 16)
        r = __builtin_amdgcn_permlane16_swap(__float_as_uint(d), __float_as_uint(s), false, false);
    else
        r = __builtin_amdgcn_permlane32_swap(__float_as_uint(d), __float_as_uint(s), false, false);
    d = __uint_as_float(r.x);
    s = __uint_as_float(r.y);
#else
    asm("v_mov_b32 %0, %1" : "=v"(s) : "v"(s));
    if constexpr (LM == 16) asm("v_permlane16_swap_b32 %0, %1" : "+v"(d), "+v"(s));
    else                    asm("v_permlane32_swap_b32 %0, %1" : "+v"(d), "+v"(s));
#endif
}

// partner value v[lane ^ LM], LM in {1,2,4,8}
template<int LM>
__device__ __forceinline__ float xfetch(float v) {
    if constexpr (LM == 1)      return dppmov<0xB1>(v);   // quad_perm [1,0,3,2]
    else if constexpr (LM == 2) return dppmov<0x4E>(v);   // quad_perm [2,3,0,1]
    else if constexpr (LM == 4)
        return __int_as_float(__builtin_amdgcn_ds_swizzle(__float_as_int(v), 0x101F));
    else                        return dppmov<0x128>(v);  // row_ror:8 == xor8
}

template<int LM>
__device__ __forceinline__ f2 xfetch2(f2 v) {
    f2 r; r.x = xfetch<LM>(v.x); r.y = xfetch<LM>(v.y); return r;
}

// (lane&LM)==0: mine=d, partner=s; else mine=s, partner=d.
template<int LM>
__device__ __forceinline__ void plswap2(f2 v, f2& d, f2& s) {
    float dx = v.x, sx = v.x; plswap<LM>(dx, sx);
    float dy = v.y, sy = v.y; plswap<LM>(dy, sy);
    d.x = dx; d.y = dy; s.x = sx; s.y = sy;
}

template<int LM>
__device__ __forceinline__ float bfly_add(float v) {
    if constexpr (LM >= 16) { float d = v, s = v; plswap<LM>(d, s); return d + s; }
    else                    return v + xfetch<LM>(v);
}

__device__ __forceinline__ float bfly_full(float v) {
    v = bfly_add<1>(v); v = bfly_add<2>(v); v = bfly_add<4>(v);
    v = bfly_add<8>(v); v = bfly_add<16>(v); v = bfly_add<32>(v);
    return v;
}

// ---------------------------------------------------------------------------
// State: 8 x float2 per lane. Amplitude k = (lane<<4) | (j<<1) | e.
// k bit0 = float2 element e; k bits1-3 = pair index j bits0-2; bits4-9 = lane.
// Wire q <-> k bit (9-q). float2 arithmetic -> v_pk_fma_f32 (2 FMA/instr).
// ---------------------------------------------------------------------------
template<int P>
__device__ __forceinline__ void rot2(f2 (&R)[8], f2 (&I)[8],
                                     const float* __restrict__ g, int lane) {
    float u00r = g[0], u00i = g[1], u01r = g[2], u01i = g[3];
    float u10r = g[4], u10i = g[5], u11r = g[6], u11i = g[7];
    if constexpr (P == 0) {
        // within-pair mix; pack rows: out.x=row0, out.y=row1
        f2 Kr0 = {u00r, u10r}, Ki0 = {u00i, u10i};
        f2 Kr1 = {u01r, u11r}, Ki1 = {u01i, u11i};
        #pragma unroll
        for (int j = 0; j < 8; ++j) {
            f2 ar = R[j], ai = I[j];
            f2 arx = {ar.x, ar.x}, ary = {ar.y, ar.y};
            f2 aix = {ai.x, ai.x}, aiy = {ai.y, ai.y};
            R[j] = Kr0*arx - Ki0*aix + Kr1*ary - Ki1*aiy;
            I[j] = Kr0*aix + Ki0*arx + Kr1*aiy + Ki1*ary;
        }
    } else if constexpr (P <= 3) {
        constexpr int m2 = 1 << (P - 1);
        #pragma unroll
        for (int j = 0; j < 8; ++j) {
            if (!(j & m2)) {
                const int j2 = j | m2;
                f2 a0 = R[j], a0i = I[j], a1 = R[j2], a1i = I[j2];
                R[j]  = u00r*a0 - u00i*a0i + u01r*a1 - u01i*a1i;
                I[j]  = u00r*a0i + u00i*a0 + u01r*a1i + u01i*a1;
                R[j2] = u10r*a0 - u10i*a0i + u11r*a1 - u11i*a1i;
                I[j2] = u10r*a0i + u10i*a0 + u11r*a1i + u11i*a1;
            }
        }
    } else if constexpr (P <= 7) {
        constexpr int LM = 1 << (P - 4);
        const bool hi = (lane & LM) != 0;
        float Ar = hi ? u11r : u00r, Ai = hi ? u11i : u00i;
        float Br = hi ? u10r : u01r, Bi = hi ? u10i : u01i;
        #pragma unroll
        for (int j = 0; j < 8; ++j) {
            f2 pr = xfetch2<LM>(R[j]), pi = xfetch2<LM>(I[j]);
            f2 mr = R[j], mi = I[j];
            R[j] = Ar*mr - Ai*mi + Br*pr - Bi*pi;
            I[j] = Ar*mi + Ai*mr + Br*pi + Bi*pr;
        }
    } else {
        constexpr int LM = 1 << (P - 4);
        const bool hi = (lane & LM) != 0;
        float Cdr = hi ? u10r : u00r, Cdi = hi ? u10i : u00i;
        float Csr = hi ? u11r : u01r, Csi = hi ? u11i : u01i;
        #pragma unroll
        for (int j = 0; j < 8; ++j) {
            f2 dr, sr, di, si;
            plswap2<LM>(R[j], dr, sr);
            plswap2<LM>(I[j], di, si);
            R[j] = Cdr*dr - Cdi*di + Csr*sr - Csi*si;
            I[j] = Cdr*di + Cdi*dr + Csr*si + Csi*sr;
        }
    }
}

template<int PC, int PT>
__device__ __forceinline__ void cnot2(f2 (&R)[8], f2 (&I)[8], int lane) {
    if constexpr (PC >= 4 && PT >= 4) {                  // lane ctrl, lane tgt
        constexpr int LM = 1 << (PT - 4);
        const bool ctrl = (lane & (1 << (PC - 4))) != 0;
        if constexpr (LM >= 16) {
            const bool t = (lane & LM) != 0;
            const bool sel = (ctrl == t);
            #pragma unroll
            for (int j = 0; j < 8; ++j) {
                f2 d, s;  plswap2<LM>(R[j], d, s);  R[j] = sel ? d : s;
                f2 di, si; plswap2<LM>(I[j], di, si); I[j] = sel ? di : si;
            }
        } else {
            #pragma unroll
            for (int j = 0; j < 8; ++j) {
                f2 pr = xfetch2<LM>(R[j]), pi = xfetch2<LM>(I[j]);
                R[j] = ctrl ? pr : R[j];
                I[j] = ctrl ? pi : I[j];
            }
        }
    } else if constexpr (PC >= 4 && PT >= 1) {           // lane ctrl, pair tgt
        constexpr int m2 = 1 << (PT - 1);
        const bool ctrl = (lane & (1 << (PC - 4))) != 0;
        #pragma unroll
        for (int j = 0; j < 8; ++j) {
            if (!(j & m2)) {
                const int j2 = j | m2;
                f2 a = R[j], b = R[j2];
                R[j] = ctrl ? b : a;  R[j2] = ctrl ? a : b;
                f2 c = I[j], d = I[j2];
                I[j] = ctrl ? d : c;  I[j2] = ctrl ? c : d;
            }
        }
    } else if constexpr (PC >= 4 && PT == 0) {           // lane ctrl, elem tgt
        const bool ctrl = (lane & (1 << (PC - 4))) != 0;
        #pragma unroll
        for (int j = 0; j < 8; ++j) {
            f2 a = R[j]; f2 sw; sw.x = a.y; sw.y = a.x; R[j] = ctrl ? sw : a;
            f2 b = I[j]; f2 sx; sx.x = b.y; sx.y = b.x; I[j] = ctrl ? sx : b;
        }
    } else if constexpr (PC >= 1 && PT >= 4) {           // pair ctrl, lane tgt
        constexpr int LM = 1 << (PT - 4);
        constexpr int cm2 = 1 << (PC - 1);
        if constexpr (LM >= 16) {
            const bool t = (lane & LM) != 0;
            #pragma unroll
            for (int j = 0; j < 8; ++j) {
                if (j & cm2) {
                    f2 d, s;  plswap2<LM>(R[j], d, s);  R[j] = t ? d : s;
                    f2 di, si; plswap2<LM>(I[j], di, si); I[j] = t ? di : si;
                }
            }
        } else {
            #pragma unroll
            for (int j = 0; j < 8; ++j) {
                if (j & cm2) { R[j] = xfetch2<LM>(R[j]); I[j] = xfetch2<LM>(I[j]); }
            }
        }
    } else if constexpr (PC == 0 && PT >= 4) {           // elem ctrl (.y), lane tgt
        constexpr int LM = 1 << (PT - 4);
        if constexpr (LM >= 16) {
            const bool t = (lane & LM) != 0;
            #pragma unroll
            for (int j = 0; j < 8; ++j) {
                float dy = R[j].y, sy = R[j].y; plswap<LM>(dy, sy); R[j].y = t ? dy : sy;
                float ey = I[j].y, fy = I[j].y; plswap<LM>(ey, fy); I[j].y = t ? ey : fy;
            }
        } else {
            #pragma unroll
            for (int j = 0; j < 8; ++j) {
                R[j].y = xfetch<LM>(R[j].y); I[j].y = xfetch<LM>(I[j].y);
            }
        }
    } else if constexpr (PC >= 1 && PT >= 1) {           // pair perm (free)
        constexpr int cm2 = 1 << (PC - 1), tm2 = 1 << (PT - 1);
        #pragma unroll
        for (int j = 0; j < 8; ++j) {
            if ((j & cm2) && !(j & tm2)) {
                const int j2 = j | tm2;
                f2 t = R[j]; R[j] = R[j2]; R[j2] = t;
                f2 u = I[j]; I[j] = I[j2]; I[j2] = u;
            }
        }
    } else if constexpr (PC >= 1 && PT == 0) {           // pair ctrl, elem swap
        constexpr int cm2 = 1 << (PC - 1);
        #pragma unroll
        for (int j = 0; j < 8; ++j) {
            if (j & cm2) {
                f2 a = R[j]; R[j].x = a.y; R[j].y = a.x;
                f2 b = I[j]; I[j].x = b.y; I[j].y = b.x;
            }
        }
    } else {                                             // elem ctrl, pair tgt
        constexpr int tm2 = 1 << (PT - 1);
        #pragma unroll
        for (int j = 0; j < 8; ++j) {
            if (!(j & tm2)) {
                const int j2 = j | tm2;
                float t = R[j].y; R[j].y = R[j2].y; R[j2].y = t;
                float u = I[j].y; I[j].y = I[j2].y; I[j2].y = u;
            }
        }
    }
}

// ---------------------------------------------------------------------------
// Main kernel: one wave per batch element; 4 waves per block.
// ---------------------------------------------------------------------------
__global__ __launch_bounds__(256) void qsim(const float* __restrict__ x,
                                            const float* __restrict__ gates,
                                            float* __restrict__ out, int B) {
    const int lane = threadIdx.x & 63;
    const int wave = threadIdx.x >> 6;
    const int row  = blockIdx.x * 4 + wave;
    if (row >= B) return;

    const float* xr = x + (size_t)row * DIM + lane * 16;
    f2 R[8], I[8];
    {
        float4 v0 = *(const float4*)(xr + 0);
        float4 v1 = *(const float4*)(xr + 4);
        float4 v2 = *(const float4*)(xr + 8);
        float4 v3 = *(const float4*)(xr + 12);
        R[0].x=v0.x; R[0].y=v0.y;  R[1].x=v0.z; R[1].y=v0.w;
        R[2].x=v1.x; R[2].y=v1.y;  R[3].x=v1.z; R[3].y=v1.w;
        R[4].x=v2.x; R[4].y=v2.y;  R[5].x=v2.z; R[5].y=v2.w;
        R[6].x=v3.x; R[6].y=v3.y;  R[7].x=v3.z; R[7].y=v3.w;
    }
    f2 n2 = R[0]*R[0];
    #pragma unroll
    for (int j = 1; j < 8; ++j) n2 += R[j]*R[j];
    float nrm = bfly_full(n2.x + n2.y);
    float inv = rsqrtf(nrm);

    // first gate (layer0, wire0, P=9): state REAL; fold inv into coefficients
    {
        const float* g = gates;
        const bool hi = (lane & 32) != 0;
        float Cdr = (hi ? g[4] : g[0]) * inv, Cdi = (hi ? g[5] : g[1]) * inv;
        float Csr = (hi ? g[6] : g[2]) * inv, Csi = (hi ? g[7] : g[3]) * inv;
        #pragma unroll
        for (int j = 0; j < 8; ++j) {
            f2 d, s; plswap2<32>(R[j], d, s);
            R[j] = Cdr*d + Csr*s;
            I[j] = Cdi*d + Csi*s;
        }
    }

    #define ROT(l, q) rot2<9 - (q)>(R, I, gates + ((l) * 10 + (q)) * 8, lane)

    // ----- layer 0 (wire0 done): Rot rest, CNOT ring r=1 -----
    ROT(0,1); ROT(0,2); ROT(0,3); ROT(0,4);
    ROT(0,5); ROT(0,6); ROT(0,7); ROT(0,8); ROT(0,9);
    cnot2<9,8>(R,I,lane); cnot2<8,7>(R,I,lane);
    cnot2<7,6>(R,I,lane); cnot2<6,5>(R,I,lane);
    cnot2<5,4>(R,I,lane); cnot2<4,3>(R,I,lane);
    cnot2<3,2>(R,I,lane); cnot2<2,1>(R,I,lane);
    cnot2<1,0>(R,I,lane); cnot2<0,9>(R,I,lane);

    // ----- layer 1: Rot all, CNOT ring r=2 -----
    ROT(1,0); ROT(1,1); ROT(1,2); ROT(1,3); ROT(1,4);
    ROT(1,5); ROT(1,6); ROT(1,7); ROT(1,8); ROT(1,9);
    cnot2<9,7>(R,I,lane); cnot2<8,6>(R,I,lane);
    cnot2<7,5>(R,I,lane); cnot2<6,4>(R,I,lane);
    cnot2<5,3>(R,I,lane); cnot2<4,2>(R,I,lane);
    cnot2<3,1>(R,I,lane); cnot2<2,0>(R,I,lane);
    cnot2<1,9>(R,I,lane); cnot2<0,8>(R,I,lane);

    #undef ROT

    // ----- probabilities (packed accumulate) -----
    // q6<->j&4, q7<->j&2, q8<->j&1, q9<->element(.y)
    f2 sum2 = {0.f, 0.f}, sa2 = {0.f, 0.f}, sb2 = {0.f, 0.f}, sc2 = {0.f, 0.f};
    #pragma unroll
    for (int j = 0; j < 8; ++j) {
        f2 t2 = R[j]*R[j] + I[j]*I[j];
        sum2 += t2;
        if (j & 4) sa2 += t2;
        if (j & 2) sb2 += t2;
        if (j & 1) sc2 += t2;
    }
    float sum = sum2.x + sum2.y;
    float s1a = sa2.x + sa2.y;   // q6
    float s1b = sb2.x + sb2.y;   // q7
    float s1c = sc2.x + sc2.y;   // q8
    float s1d = sum2.y;          // q9 (element bit)

    // ----- Walsh-Hadamard over 6 lane bits: lane 1<<(5-i) holds e_i; lane0 total
    float w = sum;
    {
        float p, sg;
        sg = (lane & 1) ? -1.f : 1.f;  p = xfetch<1>(w); w = fmaf(sg, w, p);
        sg = (lane & 2) ? -1.f : 1.f;  p = xfetch<2>(w); w = fmaf(sg, w, p);
        sg = (lane & 4) ? -1.f : 1.f;  p = xfetch<4>(w); w = fmaf(sg, w, p);
        sg = (lane & 8) ? -1.f : 1.f;  p = xfetch<8>(w); w = fmaf(sg, w, p);
        { float d = w, s = w; plswap<16>(d, s); sg = (lane & 16) ? -1.f : 1.f; w = fmaf(sg, s, d); }
        { float d = w, s = w; plswap<32>(d, s); sg = (lane & 32) ? -1.f : 1.f; w = fmaf(sg, s, d); }
    }

    float R0 = bfly_full(s1a);
    float R1 = bfly_full(s1b);
    float R2 = bfly_full(s1c);
    float R3 = bfly_full(s1d);

    float* o = out + (size_t)row * NQ;
    if (lane && lane <= 32 && !(lane & (lane - 1)))
        o[6 - __ffs(lane)] = w;            // lanes 32,16,8,4,2,1 -> e0..e5
    if (lane == 0) {
        o[6] = fmaf(-2.f, R0, w);          // w at lane0 == total prob
        o[7] = fmaf(-2.f, R1, w);
        o[8] = fmaf(-2.f, R2, w);
        o[9] = fmaf(-2.f, R3, w);
    }
}

extern "C" void kernel_launch(void* const* d_in, const int* in_sizes, int n_in,
                              void* d_out, int out_size, void* d_ws, size_t ws_size,
                              hipStream_t stream) {
    const float* x = (const float*)d_in[0];
    const float* w = (const float*)d_in[1];
    float* gates = (float*)d_ws;                  // 160 floats
    float* out = (float*)d_out;

    const int B = in_sizes[0] / DIM;              // 16384

    precompute_gates<<<1, 64, 0, stream>>>(w, gates);
    qsim<<<(B + 3) / 4, 256, 0, stream>>>(x, gates, out, B);
}

// Round 13
// 159.775 us; speedup vs baseline: 7.2007x; 1.0664x over previous
//
#include <hip/hip_runtime.h>
#include <math.h>

#define NQ 10
#define DIM 1024
#define NL 2

// ---------------------------------------------------------------------------
// Gate matrices: 8 floats per gate: u00r,u00i,u01r,u01i,u10r,u10i,u11r,u11i
// ---------------------------------------------------------------------------
__global__ void precompute_gates(const float* __restrict__ w, float* __restrict__ g) {
    int t = threadIdx.x;
    if (t < NL * NQ) {
        float phi = w[t * 3 + 0], theta = w[t * 3 + 1], omega = w[t * 3 + 2];
        float c  = cosf(0.5f * theta), s = sinf(0.5f * theta);
        float ap = 0.5f * phi, ao = 0.5f * omega;
        float cs = cosf(ap + ao), ss = sinf(ap + ao);
        float cd = cosf(ap - ao), sd = sinf(ap - ao);
        float* o = g + t * 8;
        o[0] =  c * cs;  o[1] = -c * ss;
        o[2] = -s * cd;  o[3] = -s * sd;
        o[4] =  s * cd;  o[5] = -s * sd;
        o[6] =  c * cs;  o[7] =  c * ss;
    }
}

// ---------------------------------------------------------------------------
// Cross-lane primitives (round-8/11 verified). Builtin permlane swap is
// mandatory (asm "+v","+v" coalesces equal d,s -> self-swap bug, round 6).
// NO __launch_bounds__ min-waves (round 10: forced VGPR=32 -> 3.6GB spill).
// ---------------------------------------------------------------------------
template<int CTRL>
__device__ __forceinline__ float dppmov(float v) {
    return __int_as_float(
        __builtin_amdgcn_mov_dpp(__float_as_int(v), CTRL, 0xF, 0xF, true));
}

typedef unsigned u32x2 __attribute__((ext_vector_type(2)));
typedef float f2 __attribute__((ext_vector_type(2)));

__device__ __forceinline__ f2 mk2(float a, float b) { f2 r; r.x = a; r.y = b; return r; }

template<int LM>
__device__ __forceinline__ void plswap(float& d, float& s) {
#if __has_builtin(__builtin_amdgcn_permlane16_swap) && __has_builtin(__builtin_amdgcn_permlane32_swap)
    u32x2 r;
    if constexpr (LM == 16)
        r = __builtin_amdgcn_permlane16_swap(__float_as_uint(d), __float_as_uint(s), false, false);
    else
        r = __builtin_amdgcn_permlane32_swap(__float_as_uint(d), __float_as_uint(s), false, false);
    d = __uint_as_float(r.x);
    s = __uint_as_float(r.y);
#else
    asm("v_mov_b32 %0, %1" : "=v"(s) : "v"(s));
    if constexpr (LM == 16) asm("v_permlane16_swap_b32 %0, %1" : "+v"(d), "+v"(s));
    else                    asm("v_permlane32_swap_b32 %0, %1" : "+v"(d), "+v"(s));
#endif
}

// partner value v[lane ^ LM], LM in {1,2,4,8} (used by layer-0 rots + WHT)
template<int LM>
__device__ __forceinline__ float xfetch(float v) {
    if constexpr (LM == 1)      return dppmov<0xB1>(v);
    else if constexpr (LM == 2) return dppmov<0x4E>(v);
    else if constexpr (LM == 4)
        return __int_as_float(__builtin_amdgcn_ds_swizzle(__float_as_int(v), 0x101F));
    else                        return dppmov<0x128>(v);
}

template<int LM>
__device__ __forceinline__ f2 xfetch2(f2 v) {
    f2 r; r.x = xfetch<LM>(v.x); r.y = xfetch<LM>(v.y); return r;
}

template<int LM>
__device__ __forceinline__ void plswap2(f2 v, f2& d, f2& s) {
    float dx = v.x, sx = v.x; plswap<LM>(dx, sx);
    float dy = v.y, sy = v.y; plswap<LM>(dy, sy);
    d.x = dx; d.y = dy; s.x = sx; s.y = sy;
}

template<int LM>
__device__ __forceinline__ float bfly_add(float v) {
    if constexpr (LM >= 16) { float d = v, s = v; plswap<LM>(d, s); return d + s; }
    else                    return v + xfetch<LM>(v);
}

__device__ __forceinline__ float bfly_full(float v) {
    v = bfly_add<1>(v); v = bfly_add<2>(v); v = bfly_add<4>(v);
    v = bfly_add<8>(v); v = bfly_add<16>(v); v = bfly_add<32>(v);
    return v;
}

// Arbitrary lane-xor partner fetch for layer-1 masks.
// ds_swizzle BitMode: offset = (xor<<10) | 0x1F handles any xor mask <= 31.
// Mask 48 (bits 4,5): swz(xor16) then permlane32_swap; partner = bit5? d : s.
template<int LM>
__device__ __forceinline__ float lanefetch(float v, int lane) {
    if constexpr (LM == 0)       return v;
    else if constexpr (LM == 1)  return dppmov<0xB1>(v);
    else if constexpr (LM == 2)  return dppmov<0x4E>(v);
    else if constexpr (LM == 3)  return dppmov<0x1B>(v);     // quad_perm [3,2,1,0]
    else if constexpr (LM == 6)
        return __int_as_float(__builtin_amdgcn_ds_swizzle(__float_as_int(v), 0x181F));
    else if constexpr (LM == 12)
        return __int_as_float(__builtin_amdgcn_ds_swizzle(__float_as_int(v), 0x301F));
    else if constexpr (LM == 24)
        return __int_as_float(__builtin_amdgcn_ds_swizzle(__float_as_int(v), 0x601F));
    else { // LM == 48
        float t = __int_as_float(__builtin_amdgcn_ds_swizzle(__float_as_int(v), 0x401F));
        float d = t, s = t; plswap<32>(d, s);
        return (lane & 32) ? d : s;
    }
}

// Generalized WHT over the 6 lane bits: afterwards lane L holds
// sum_l (-1)^{popc(L & l)} x(l).
__device__ __forceinline__ float wht64(float w, int lane) {
    float p, sg;
    sg = (lane & 1) ? -1.f : 1.f;  p = xfetch<1>(w); w = fmaf(sg, w, p);
    sg = (lane & 2) ? -1.f : 1.f;  p = xfetch<2>(w); w = fmaf(sg, w, p);
    sg = (lane & 4) ? -1.f : 1.f;  p = xfetch<4>(w); w = fmaf(sg, w, p);
    sg = (lane & 8) ? -1.f : 1.f;  p = xfetch<8>(w); w = fmaf(sg, w, p);
    { float d = w, s = w; plswap<16>(d, s); sg = (lane & 16) ? -1.f : 1.f; w = fmaf(sg, s, d); }
    { float d = w, s = w; plswap<32>(d, s); sg = (lane & 32) ? -1.f : 1.f; w = fmaf(sg, s, d); }
    return w;
}

// ---------------------------------------------------------------------------
// State: amplitude k = (lane<<4)|(j<<1)|e; R[8],I[8] f2 (e = f2 element).
// Wire q <-> k bit (9-q). Layer-0 rot on bit P (sigma = I).
// ---------------------------------------------------------------------------
template<int P>
__device__ __forceinline__ void rot2(f2 (&R)[8], f2 (&I)[8],
                                     const float* __restrict__ g, int lane) {
    float u00r = g[0], u00i = g[1], u01r = g[2], u01i = g[3];
    float u10r = g[4], u10i = g[5], u11r = g[6], u11i = g[7];
    if constexpr (P == 0) {
        f2 Kr0 = mk2(u00r, u10r), Ki0 = mk2(u00i, u10i);
        f2 Kr1 = mk2(u01r, u11r), Ki1 = mk2(u01i, u11i);
        #pragma unroll
        for (int j = 0; j < 8; ++j) {
            f2 ar = R[j], ai = I[j];
            f2 arx = mk2(ar.x, ar.x), ary = mk2(ar.y, ar.y);
            f2 aix = mk2(ai.x, ai.x), aiy = mk2(ai.y, ai.y);
            R[j] = Kr0*arx - Ki0*aix + Kr1*ary - Ki1*aiy;
            I[j] = Kr0*aix + Ki0*arx + Kr1*aiy + Ki1*ary;
        }
    } else if constexpr (P <= 3) {
        constexpr int m2 = 1 << (P - 1);
        #pragma unroll
        for (int j = 0; j < 8; ++j) {
            if (!(j & m2)) {
                const int j2 = j | m2;
                f2 a0 = R[j], a0i = I[j], a1 = R[j2], a1i = I[j2];
                R[j]  = u00r*a0 - u00i*a0i + u01r*a1 - u01i*a1i;
                I[j]  = u00r*a0i + u00i*a0 + u01r*a1i + u01i*a1;
                R[j2] = u10r*a0 - u10i*a0i + u11r*a1 - u11i*a1i;
                I[j2] = u10r*a0i + u10i*a0 + u11r*a1i + u11i*a1;
            }
        }
    } else if constexpr (P <= 7) {
        constexpr int LM = 1 << (P - 4);
        const bool hi = (lane & LM) != 0;
        float Ar = hi ? u11r : u00r, Ai = hi ? u11i : u00i;
        float Br = hi ? u10r : u01r, Bi = hi ? u10i : u01i;
        #pragma unroll
        for (int j = 0; j < 8; ++j) {
            f2 pr = xfetch2<LM>(R[j]), pi = xfetch2<LM>(I[j]);
            f2 mr = R[j], mi = I[j];
            R[j] = Ar*mr - Ai*mi + Br*pr - Bi*pi;
            I[j] = Ar*mi + Ai*mr + Br*pi + Bi*pr;
        }
    } else {
        constexpr int LM = 1 << (P - 4);
        const bool hi = (lane & LM) != 0;
        float Cdr = hi ? u10r : u00r, Cdi = hi ? u10i : u00i;
        float Csr = hi ? u11r : u01r, Csi = hi ? u11i : u01i;
        #pragma unroll
        for (int j = 0; j < 8; ++j) {
            f2 dr, sr, di, si;
            plswap2<LM>(R[j], dr, sr);
            plswap2<LM>(I[j], di, si);
            R[j] = Cdr*dr - Cdi*di + Csr*sr - Csi*si;
            I[j] = Cdr*di + Cdi*dr + Csr*si + Csi*sr;
        }
    }
}

// ---------------------------------------------------------------------------
// Layer-1 rot through the virtualized ring-1 CNOTs (GF(2) relabeling).
// Pair mask m = sigma1(e_p) split: LMASK (lane xor), JMASK (j xor), EB (elem).
// Row selector f = row p of sigma1^-1 split (FL,FJ,FE):
//   role(k) = popc(lane&FL) ^ popc(j&FJ) ^ (FE & e)
// ---------------------------------------------------------------------------
template<int LMASK, int JMASK, int EB, int FL, int FJ, int FE>
__device__ __forceinline__ void gate1(f2 (&R)[8], f2 (&I)[8],
                                      const float* __restrict__ g, int lane) {
    float u00r = g[0], u00i = g[1], u01r = g[2], u01i = g[3];
    float u10r = g[4], u10i = g[5], u11r = g[6], u11i = g[7];
    const bool lp = (__popc(lane & FL) & 1) != 0;
    float ArL = lp ? u11r : u00r, ArH = lp ? u00r : u11r;
    float AiL = lp ? u11i : u00i, AiH = lp ? u00i : u11i;
    float BrL = lp ? u10r : u01r, BrH = lp ? u01r : u10r;
    float BiL = lp ? u10i : u01i, BiH = lp ? u01i : u10i;
    f2 cAr0, cAi0, cBr0, cBi0, cAr1, cAi1, cBr1, cBi1;
    if constexpr (FE) {
        cAr0 = mk2(ArL, ArH); cAi0 = mk2(AiL, AiH);
        cBr0 = mk2(BrL, BrH); cBi0 = mk2(BiL, BiH);
        cAr1 = mk2(ArH, ArL); cAi1 = mk2(AiH, AiL);
        cBr1 = mk2(BrH, BrL); cBi1 = mk2(BiH, BiL);
    } else {
        cAr0 = mk2(ArL, ArL); cAi0 = mk2(AiL, AiL);
        cBr0 = mk2(BrL, BrL); cBi0 = mk2(BiL, BiL);
        cAr1 = mk2(ArH, ArH); cAi1 = mk2(AiH, AiH);
        cBr1 = mk2(BrH, BrH); cBi1 = mk2(BiH, BiH);
    }

    if constexpr (JMASK == 0) {
        #pragma unroll
        for (int j = 0; j < 8; ++j) {
            const int jp = __builtin_popcount(j & FJ) & 1;   // compile-time
            f2 mr = R[j], mi = I[j];
            f2 pr, pi;
            if constexpr (EB) {
                pr.x = lanefetch<LMASK>(mr.y, lane); pr.y = lanefetch<LMASK>(mr.x, lane);
                pi.x = lanefetch<LMASK>(mi.y, lane); pi.y = lanefetch<LMASK>(mi.x, lane);
            } else {
                pr.x = lanefetch<LMASK>(mr.x, lane); pr.y = lanefetch<LMASK>(mr.y, lane);
                pi.x = lanefetch<LMASK>(mi.x, lane); pi.y = lanefetch<LMASK>(mi.y, lane);
            }
            f2 Ar = jp ? cAr1 : cAr0, Ai = jp ? cAi1 : cAi0;
            f2 Br = jp ? cBr1 : cBr0, Bi = jp ? cBi1 : cBi0;
            R[j] = Ar*mr - Ai*mi + Br*pr - Bi*pi;
            I[j] = Ar*mi + Ai*mr + Br*pi + Bi*pr;
        }
    } else {
        #pragma unroll
        for (int j = 0; j < 8; ++j) {
            const int j2 = j ^ JMASK;
            if (j < j2) {
                f2 aR = R[j], aI = I[j], bR = R[j2], bI = I[j2];
                f2 paR, paI, pbR, pbI;
                if constexpr (EB) {
                    paR.x = lanefetch<LMASK>(bR.y, lane); paR.y = lanefetch<LMASK>(bR.x, lane);
                    paI.x = lanefetch<LMASK>(bI.y, lane); paI.y = lanefetch<LMASK>(bI.x, lane);
                    pbR.x = lanefetch<LMASK>(aR.y, lane); pbR.y = lanefetch<LMASK>(aR.x, lane);
                    pbI.x = lanefetch<LMASK>(aI.y, lane); pbI.y = lanefetch<LMASK>(aI.x, lane);
                } else {
                    paR.x = lanefetch<LMASK>(bR.x, lane); paR.y = lanefetch<LMASK>(bR.y, lane);
                    paI.x = lanefetch<LMASK>(bI.x, lane); paI.y = lanefetch<LMASK>(bI.y, lane);
                    pbR.x = lanefetch<LMASK>(aR.x, lane); pbR.y = lanefetch<LMASK>(aR.y, lane);
                    pbI.x = lanefetch<LMASK>(aI.x, lane); pbI.y = lanefetch<LMASK>(aI.y, lane);
                }
                const int jpa = __builtin_popcount(j  & FJ) & 1;
                const int jpb = __builtin_popcount(j2 & FJ) & 1;
                f2 Ara = jpa ? cAr1 : cAr0, Aia = jpa ? cAi1 : cAi0;
                f2 Bra = jpa ? cBr1 : cBr0, Bia = jpa ? cBi1 : cBi0;
                f2 Arb = jpb ? cAr1 : cAr0, Aib = jpb ? cAi1 : cAi0;
                f2 Brb = jpb ? cBr1 : cBr0, Bib = jpb ? cBi1 : cBi0;
                R[j]  = Ara*aR - Aia*aI + Bra*paR - Bia*paI;
                I[j]  = Ara*aI + Aia*aR + Bra*paI + Bia*paR;
                R[j2] = Arb*bR - Aib*bI + Brb*pbR - Bib*pbI;
                I[j2] = Arb*bI + Aib*bR + Brb*pbI + Bib*pbR;
            }
        }
    }
}

// ---------------------------------------------------------------------------
// Main kernel. CNOT rings are NEVER executed: ring1 absorbed into layer-1
// masks/selectors (sigma1), ring2 into the measurement functionals.
// ---------------------------------------------------------------------------
__global__ __launch_bounds__(256) void qsim(const float* __restrict__ x,
                                            const float* __restrict__ gates,
                                            float* __restrict__ out, int B) {
    const int lane = threadIdx.x & 63;
    const int wave = threadIdx.x >> 6;
    const int row  = blockIdx.x * 4 + wave;
    if (row >= B) return;

    const float* xr = x + (size_t)row * DIM + lane * 16;
    f2 R[8], I[8];
    {
        float4 v0 = *(const float4*)(xr + 0);
        float4 v1 = *(const float4*)(xr + 4);
        float4 v2 = *(const float4*)(xr + 8);
        float4 v3 = *(const float4*)(xr + 12);
        R[0] = mk2(v0.x, v0.y); R[1] = mk2(v0.z, v0.w);
        R[2] = mk2(v1.x, v1.y); R[3] = mk2(v1.z, v1.w);
        R[4] = mk2(v2.x, v2.y); R[5] = mk2(v2.z, v2.w);
        R[6] = mk2(v3.x, v3.y); R[7] = mk2(v3.z, v3.w);
    }
    f2 n2 = R[0]*R[0];
    #pragma unroll
    for (int j = 1; j < 8; ++j) n2 += R[j]*R[j];
    float inv = rsqrtf(bfly_full(n2.x + n2.y));

    // first gate (layer0, wire0, P=9): real state; fold inv into coefficients
    {
        const float* g = gates;
        const bool hi = (lane & 32) != 0;
        float Cdr = (hi ? g[4] : g[0]) * inv, Cdi = (hi ? g[5] : g[1]) * inv;
        float Csr = (hi ? g[6] : g[2]) * inv, Csi = (hi ? g[7] : g[3]) * inv;
        #pragma unroll
        for (int j = 0; j < 8; ++j) {
            f2 d, s; plswap2<32>(R[j], d, s);
            R[j] = Cdr*d + Csr*s;
            I[j] = Cdi*d + Csi*s;
        }
    }

    #define ROT0(q) rot2<9 - (q)>(R, I, gates + (q) * 8, lane)
    ROT0(1); ROT0(2); ROT0(3); ROT0(4);
    ROT0(5); ROT0(6); ROT0(7); ROT0(8); ROT0(9);
    #undef ROT0

    // ----- layer 1 through virtual ring-1 -----
    const float* g1 = gates + 10 * 8;
    gate1<48, 0, 0, 31, 7, 1>(R, I, g1 + 0*8, lane);   // wire0: m={8,9}  f={0..8}
    gate1<24, 0, 0, 48, 0, 0>(R, I, g1 + 1*8, lane);   // wire1: m={7,8}  f={8,9}
    gate1<12, 0, 0, 56, 0, 0>(R, I, g1 + 2*8, lane);   // wire2: m={6,7}  f={7,8,9}
    gate1< 6, 0, 0, 60, 0, 0>(R, I, g1 + 3*8, lane);   // wire3: m={5,6}  f={6..9}
    gate1< 3, 0, 0, 62, 0, 0>(R, I, g1 + 4*8, lane);   // wire4: m={4,5}  f={5..9}
    gate1< 1, 4, 0, 63, 0, 0>(R, I, g1 + 5*8, lane);   // wire5: m={3,4}  f={4..9}
    gate1< 0, 6, 0, 63, 4, 0>(R, I, g1 + 6*8, lane);   // wire6: m={2,3}  f={3..9}
    gate1< 0, 3, 0, 63, 6, 0>(R, I, g1 + 7*8, lane);   // wire7: m={1,2}  f={2..9}
    gate1< 0, 1, 1, 63, 7, 0>(R, I, g1 + 8*8, lane);   // wire8: m={0,1}  f={1..9}
    gate1<48, 0, 1, 63, 7, 1>(R, I, g1 + 9*8, lane);   // wire9: m={0,8,9} f=all

    // ----- measurement through virtual ring-1+ring-2 -----
    //  q0:(fl6, fj3,fe0) q1:(3,1,1) q2:(39,7,1) q3:(12,0,0) q4:(25,7,1)
    //  q5:(51,0,0) q6:(38,3,1) q7:(12,6,0) q8:(25,4,1) q9:(51,1,1)
    f2 ac0 = mk2(0.f,0.f), ac1 = ac0, ac3 = ac0, ac4 = ac0, ac6 = ac0, ac7 = ac0;
    #pragma unroll
    for (int j = 0; j < 8; ++j) {
        f2 t2 = R[j]*R[j] + I[j]*I[j];
        ac0 += t2;
        if (__builtin_popcount(j & 1) & 1) ac1 -= t2; else ac1 += t2;
        if (__builtin_popcount(j & 3) & 1) ac3 -= t2; else ac3 += t2;
        if (__builtin_popcount(j & 4) & 1) ac4 -= t2; else ac4 += t2;
        if (__builtin_popcount(j & 6) & 1) ac6 -= t2; else ac6 += t2;
        if (__builtin_popcount(j & 7) & 1) ac7 -= t2; else ac7 += t2;
    }
    // groups (fj,fe): W1=(3,0) W2=(1,1) W3=(7,1) W4=(0,0) W5=(3,1) W6=(6,0) W7=(4,1)
    float W1 = wht64(ac3.x + ac3.y, lane);
    float W2 = wht64(ac1.x - ac1.y, lane);
    float W3 = wht64(ac7.x - ac7.y, lane);
    float W4 = wht64(ac0.x + ac0.y, lane);
    float W5 = wht64(ac3.x - ac3.y, lane);
    float W6 = wht64(ac6.x + ac6.y, lane);
    float W7 = wht64(ac4.x - ac4.y, lane);

    float* o = out + (size_t)row * NQ;
    if      (lane == 6)  { o[0] = W1; }
    else if (lane == 3)  { o[1] = W2; }
    else if (lane == 51) { o[9] = W2; o[5] = W4; }
    else if (lane == 39) { o[2] = W3; }
    else if (lane == 25) { o[4] = W3; o[8] = W7; }
    else if (lane == 12) { o[3] = W4; o[7] = W6; }
    else if (lane == 38) { o[6] = W5; }
}

extern "C" void kernel_launch(void* const* d_in, const int* in_sizes, int n_in,
                              void* d_out, int out_size, void* d_ws, size_t ws_size,
                              hipStream_t stream) {
    const float* x = (const float*)d_in[0];
    const float* w = (const float*)d_in[1];
    float* gates = (float*)d_ws;                  // 160 floats
    float* out = (float*)d_out;

    const int B = in_sizes[0] / DIM;              // 16384

    precompute_gates<<<1, 64, 0, stream>>>(w, gates);
    qsim<<<(B + 3) / 4, 256, 0, stream>>>(x, gates, out, B);
}